// Round 1
// baseline (53046.307 us; speedup 1.0000x reference)
//
#include <hip/hip_runtime.h>
#include <hip/hip_cooperative_groups.h>

namespace cg = cooperative_groups;

#define T_STEPS 800
#define BATCH   32
#define FEAT    161
#define UNITS   1024
#define CLIPV   20.0f

// ---------------------------------------------------------------------------
// K1: transpose U (1024x1024) -> Ut so the recurrent dot-product can use
// float4 loads along k.
// ---------------------------------------------------------------------------
__global__ __launch_bounds__(256) void transpose_u(const float* __restrict__ U,
                                                   float* __restrict__ Ut) {
    __shared__ float tile[32][33];
    int bx = blockIdx.x, by = blockIdx.y;
    int lx = threadIdx.x & 31;
    int ly4 = (threadIdx.x >> 5) * 4;   // 8 groups of 4 rows
    #pragma unroll
    for (int j = 0; j < 4; ++j) {
        int r = by * 32 + ly4 + j;
        tile[ly4 + j][lx] = U[(size_t)r * UNITS + bx * 32 + lx];
    }
    __syncthreads();
    #pragma unroll
    for (int j = 0; j < 4; ++j) {
        int r = bx * 32 + ly4 + j;
        Ut[(size_t)r * UNITS + by * 32 + lx] = tile[lx][ly4 + j];
    }
}

// ---------------------------------------------------------------------------
// K2: xW[t][b][u] = inputs[b][t][:] @ W[:,u] + bias[u]
// grid (800, 4): block = (t, group of 8 b). 256 threads, each does 4 u x 8 b.
// ---------------------------------------------------------------------------
__global__ __launch_bounds__(256) void xw_gemm(const float* __restrict__ inp,
                                               const float* __restrict__ W,
                                               const float* __restrict__ bias,
                                               float* __restrict__ xW) {
    __shared__ float xs[8 * FEAT];
    int t = blockIdx.x;
    int b0 = blockIdx.y * 8;
    int tid = threadIdx.x;

    for (int i = tid; i < 8 * FEAT; i += 256) {
        int j = i / FEAT;
        int f = i - j * FEAT;
        xs[i] = inp[((size_t)(b0 + j) * T_STEPS + t) * FEAT + f];
    }
    __syncthreads();

    float bv[4];
    #pragma unroll
    for (int c = 0; c < 4; ++c) bv[c] = bias[tid + c * 256];

    float acc[8][4];
    #pragma unroll
    for (int j = 0; j < 8; ++j)
        #pragma unroll
        for (int c = 0; c < 4; ++c) acc[j][c] = bv[c];

    for (int f = 0; f < FEAT; ++f) {
        float w0 = W[(size_t)f * UNITS + tid];
        float w1 = W[(size_t)f * UNITS + tid + 256];
        float w2 = W[(size_t)f * UNITS + tid + 512];
        float w3 = W[(size_t)f * UNITS + tid + 768];
        #pragma unroll
        for (int j = 0; j < 8; ++j) {
            float xv = xs[j * FEAT + f];
            acc[j][0] += xv * w0;
            acc[j][1] += xv * w1;
            acc[j][2] += xv * w2;
            acc[j][3] += xv * w3;
        }
    }

    #pragma unroll
    for (int j = 0; j < 8; ++j)
        #pragma unroll
        for (int c = 0; c < 4; ++c)
            xW[((size_t)t * BATCH + b0 + j) * UNITS + tid + c * 256] = acc[j][c];
}

// ---------------------------------------------------------------------------
// K3: persistent cooperative recurrent scan, fwd+bwd together.
// 256 blocks x 512 threads. Block bk owns a 16-row x 16-col tile of H_next,
// where row = (dir, b) in [0,64) and col = u in [0,1024).
// Each output element is computed by 2 threads (k split in halves), combined
// through LDS. h double-buffered in ws; one grid.sync() per timestep.
// ---------------------------------------------------------------------------
__global__ __launch_bounds__(512, 1) void rnn_scan(const float* __restrict__ xW,
                                                   const float* __restrict__ Ut,
                                                   float* __restrict__ hbuf,
                                                   float* __restrict__ out) {
    cg::grid_group grid = cg::this_grid();
    __shared__ float part[256];

    int tid  = threadIdx.x;
    int bk   = blockIdx.x;
    int oidx = tid & 255;    // which of the 256 outputs of this block
    int kh   = tid >> 8;     // k-half: 0 -> k in [0,512), 1 -> [512,1024)

    int u   = ((bk & 63) << 4) | (oidx & 15);
    int row = ((bk >> 6) << 4) | (oidx >> 4);
    int dir = row >> 5;      // 0 = forward, 1 = backward
    int b   = row & 31;

    const size_t HSTATE = (size_t)2 * BATCH * UNITS;   // one buffer: [dir][b][u]
    const size_t hoff   = (size_t)(dir * BATCH + b) * UNITS;

    // zero-init buffer 0 (ws is poisoned before every timed call)
    if (kh == 0) hbuf[hoff + u] = 0.f;
    grid.sync();

    const float4* urow = (const float4*)(Ut + (size_t)u * UNITS) + kh * 128;

    int cur = 0;
    for (int t = 0; t < T_STEPS; ++t) {
        int xt = dir ? (T_STEPS - 1 - t) : t;
        const float4* hrow =
            (const float4*)(hbuf + (size_t)cur * HSTATE + hoff) + kh * 128;

        float acc = 0.f;
        #pragma unroll 8
        for (int k4 = 0; k4 < 128; ++k4) {
            float4 hv = hrow[k4];
            float4 uv = urow[k4];
            acc += hv.x * uv.x + hv.y * uv.y + hv.z * uv.z + hv.w * uv.w;
        }

        if (kh) part[oidx] = acc;
        __syncthreads();
        if (!kh) {
            float a = acc + part[oidx] +
                      xW[((size_t)xt * BATCH + b) * UNITS + u];
            a = fminf(fmaxf(a, 0.f), CLIPV);
            hbuf[(size_t)(1 - cur) * HSTATE + hoff + u] = a;
        }
        cur ^= 1;
        grid.sync();   // also serves as the block barrier protecting part[]
    }

    // cur flipped 800 times (even) -> final state is in buffer 0 (cur == 0)
    if (kh == 0 && dir == 0) {
        size_t base = (size_t)cur * HSTATE;
        float hf = hbuf[base + (size_t)b * UNITS + u];
        float hb = hbuf[base + (size_t)(BATCH + b) * UNITS + u];
        out[(size_t)b * UNITS + u] = hf + hb;
    }
}

// ---------------------------------------------------------------------------
extern "C" void kernel_launch(void* const* d_in, const int* in_sizes, int n_in,
                              void* d_out, int out_size, void* d_ws, size_t ws_size,
                              hipStream_t stream) {
    const float* inp  = (const float*)d_in[0];   // [32][800][161]
    const float* W    = (const float*)d_in[1];   // [161][1024]
    const float* U    = (const float*)d_in[2];   // [1024][1024]
    const float* bias = (const float*)d_in[3];   // [1024]
    float* out = (float*)d_out;                  // [32][1024]

    float* Ut   = (float*)d_ws;                          // 1024*1024 floats (4 MB)
    float* xW   = Ut + (size_t)UNITS * UNITS;            // 800*32*1024 floats (~105 MB)
    float* hbuf = xW + (size_t)T_STEPS * BATCH * UNITS;  // 2*2*32*1024 floats (512 KB)

    transpose_u<<<dim3(32, 32), 256, 0, stream>>>(U, Ut);
    xw_gemm<<<dim3(800, 4), 256, 0, stream>>>(inp, W, bias, xW);

    void* args[] = {(void*)&xW, (void*)&Ut, (void*)&hbuf, (void*)&out};
    hipLaunchCooperativeKernel((const void*)rnn_scan, dim3(256), dim3(512),
                               args, 0, stream);
}

// Round 2
// 45959.308 us; speedup vs baseline: 1.1542x; 1.1542x over previous
//
#include <hip/hip_runtime.h>

#define T_STEPS  800
#define BATCH    32
#define FEAT     161
#define UNITS    1024
#define CLIPV    20.0f

#define NBLOCKS  256
#define NTHREADS 512
// tile: 4 rows x 64 u per block; k split 8 ways -> 128 k per thread
#define ROWS_PB  4
#define U_PB     64
#define KC_N     8
// padded LDS layout: per row, 8 chunks of (128 data + 4 pad) dwords -> bank-conflict-free
#define CHUNK_DW 132
#define ROW_DW   (KC_N * CHUNK_DW)   // 1056 dwords per row

__device__ __forceinline__ float ld_agent(const float* p) {
    return __hip_atomic_load(p, __ATOMIC_RELAXED, __HIP_MEMORY_SCOPE_AGENT);
}
__device__ __forceinline__ void st_agent(float* p, float v) {
    __hip_atomic_store(p, v, __ATOMIC_RELAXED, __HIP_MEMORY_SCOPE_AGENT);
}

// ---------------------------------------------------------------------------
__global__ __launch_bounds__(256) void init_ws(float* hbuf, unsigned* bar) {
    int gid = blockIdx.x * 256 + threadIdx.x;
    for (int i = gid; i < 2 * BATCH * UNITS; i += 64 * 256) hbuf[i] = 0.f;
    if (gid < 576) bar[gid] = 0u;
}

// ---------------------------------------------------------------------------
__global__ __launch_bounds__(256) void transpose_u(const float* __restrict__ U,
                                                   float* __restrict__ Ut) {
    __shared__ float tile[32][33];
    int bx = blockIdx.x, by = blockIdx.y;
    int lx = threadIdx.x & 31;
    int ly4 = (threadIdx.x >> 5) * 4;
    #pragma unroll
    for (int j = 0; j < 4; ++j) {
        int r = by * 32 + ly4 + j;
        tile[ly4 + j][lx] = U[(size_t)r * UNITS + bx * 32 + lx];
    }
    __syncthreads();
    #pragma unroll
    for (int j = 0; j < 4; ++j) {
        int r = bx * 32 + ly4 + j;
        Ut[(size_t)r * UNITS + by * 32 + lx] = tile[lx][ly4 + j];
    }
}

// ---------------------------------------------------------------------------
__global__ __launch_bounds__(256) void xw_gemm(const float* __restrict__ inp,
                                               const float* __restrict__ W,
                                               const float* __restrict__ bias,
                                               float* __restrict__ xW) {
    __shared__ float xs[8 * FEAT];
    int t = blockIdx.x;
    int b0 = blockIdx.y * 8;
    int tid = threadIdx.x;

    for (int i = tid; i < 8 * FEAT; i += 256) {
        int j = i / FEAT;
        int f = i - j * FEAT;
        xs[i] = inp[((size_t)(b0 + j) * T_STEPS + t) * FEAT + f];
    }
    __syncthreads();

    float bv[4];
    #pragma unroll
    for (int c = 0; c < 4; ++c) bv[c] = bias[tid + c * 256];

    float acc[8][4];
    #pragma unroll
    for (int j = 0; j < 8; ++j)
        #pragma unroll
        for (int c = 0; c < 4; ++c) acc[j][c] = bv[c];

    for (int f = 0; f < FEAT; ++f) {
        float w0 = W[(size_t)f * UNITS + tid];
        float w1 = W[(size_t)f * UNITS + tid + 256];
        float w2 = W[(size_t)f * UNITS + tid + 512];
        float w3 = W[(size_t)f * UNITS + tid + 768];
        #pragma unroll
        for (int j = 0; j < 8; ++j) {
            float xv = xs[j * FEAT + f];
            acc[j][0] += xv * w0;
            acc[j][1] += xv * w1;
            acc[j][2] += xv * w2;
            acc[j][3] += xv * w3;
        }
    }

    #pragma unroll
    for (int j = 0; j < 8; ++j)
        #pragma unroll
        for (int c = 0; c < 4; ++c)
            xW[((size_t)t * BATCH + b0 + j) * UNITS + tid + c * 256] = acc[j][c];
}

// ---------------------------------------------------------------------------
// Persistent recurrent scan. 256 blocks x 512 threads, 1 block/CU.
// Block (rg, bu): rows [rg*4, rg*4+4), u [bu*64, bu*64+64). row = dir*32 + b.
// Thread (ul, kc): u = bu*64+ul, k-range [kc*128, kc*128+128).
// Ut slice lives in 32 float4 registers per thread (loaded once).
// h state double-buffered in global ws; all h traffic uses agent-scope (sc1)
// loads/stores so no cache fences / L2 invalidates are ever needed.
// Grid barrier: two-level monotone counters (16 leaves -> root -> gen).
__global__ __launch_bounds__(NTHREADS, 2) void rnn_scan(
        const float* __restrict__ xW, const float* __restrict__ Ut,
        float* __restrict__ hbuf, unsigned* __restrict__ bar,
        float* __restrict__ out) {
    __shared__ float4 h_lds4[ROWS_PB * (ROW_DW / 4)];   // 4 rows, padded, 16.9 KB
    float* h_lds = (float*)h_lds4;

    const int tid = threadIdx.x;
    const int bk  = blockIdx.x;
    const int kc  = tid & 7;          // k-chunk 0..7
    const int ul  = tid >> 3;         // u-local 0..63
    const int bu  = bk & 15;          // u-group
    const int rg  = bk >> 4;          // row-group 0..15
    const int row_base = rg * ROWS_PB;
    const int u_global = bu * U_PB + ul;
    const int dir = row_base >> 5;    // uniform per block (4 | 32)

    // --- load Ut fragment into registers: Ut[u_global][kc*128 .. +128) ---
    float4 ufr[32];
    {
        const float4* usrc =
            (const float4*)(Ut + (size_t)u_global * UNITS + kc * 128);
        #pragma unroll
        for (int i = 0; i < 32; ++i) ufr[i] = usrc[i];
    }

    const size_t HS = (size_t)2 * BATCH * UNITS;   // 65536 floats per buffer
    unsigned* leaf = bar + (bk & 15) * 32;         // 128 B apart
    unsigned* root = bar + 512;
    unsigned* gen  = bar + 544;

    for (int t = 0; t < T_STEPS; ++t) {
        // ---- stage this block's 4 h rows into padded LDS ----
        const float* hsrc = hbuf + (size_t)(t & 1) * HS + (size_t)row_base * UNITS;
        #pragma unroll
        for (int j = 0; j < 8; ++j) {
            int idx = j * NTHREADS + tid;          // 0..4095
            int r = idx >> 10, k = idx & 1023;
            float v = ld_agent(hsrc + idx);
            h_lds[r * ROW_DW + (k >> 7) * CHUNK_DW + (k & 127)] = v;
        }
        __syncthreads();

        // ---- prefetch xW (only combining lanes need it) ----
        const int xt = dir ? (T_STEPS - 1 - t) : t;
        float xv[ROWS_PB];
        if (kc == 0) {
            #pragma unroll
            for (int r = 0; r < ROWS_PB; ++r) {
                int b = (row_base + r) & 31;
                xv[r] = xW[(size_t)xt * (BATCH * UNITS) + b * UNITS + u_global];
            }
        }

        // ---- partial dot products: 4 rows x 128 k ----
        float acc[ROWS_PB] = {0.f, 0.f, 0.f, 0.f};
        const float4* hb = h_lds4 + kc * (CHUNK_DW / 4);   // kc*33
        #pragma unroll
        for (int i = 0; i < 32; ++i) {
            #pragma unroll
            for (int r = 0; r < ROWS_PB; ++r) {
                float4 h4 = hb[r * (ROW_DW / 4) + i];
                acc[r] = fmaf(h4.x, ufr[i].x,
                         fmaf(h4.y, ufr[i].y,
                         fmaf(h4.z, ufr[i].z,
                         fmaf(h4.w, ufr[i].w, acc[r]))));
            }
        }

        // ---- reduce across the 8 k-chunks, clip, store h_next ----
        float* hdst = hbuf + (size_t)((t & 1) ^ 1) * HS;
        #pragma unroll
        for (int r = 0; r < ROWS_PB; ++r) {
            float a = acc[r];
            a += __shfl_xor(a, 1, 8);
            a += __shfl_xor(a, 2, 8);
            a += __shfl_xor(a, 4, 8);
            if (kc == 0) {
                float hv = fminf(fmaxf(a + xv[r], 0.f), CLIPV);
                st_agent(hdst + (size_t)(row_base + r) * UNITS + u_global, hv);
            }
        }
        __syncthreads();   // drains every wave's sc1 stores (vmcnt 0) + LDS reads

        // ---- two-level monotone grid barrier ----
        if (tid == 0) {
            unsigned tgt16 = 16u * (unsigned)(t + 1);
            unsigned old = __hip_atomic_fetch_add(leaf, 1u, __ATOMIC_RELAXED,
                                                  __HIP_MEMORY_SCOPE_AGENT);
            if (old == tgt16 - 1u) {
                unsigned rold = __hip_atomic_fetch_add(root, 1u, __ATOMIC_RELAXED,
                                                       __HIP_MEMORY_SCOPE_AGENT);
                if (rold == tgt16 - 1u)
                    __hip_atomic_store(gen, (unsigned)(t + 1), __ATOMIC_RELAXED,
                                       __HIP_MEMORY_SCOPE_AGENT);
            }
            while (__hip_atomic_load(gen, __ATOMIC_RELAXED,
                                     __HIP_MEMORY_SCOPE_AGENT) < (unsigned)(t + 1))
                __builtin_amdgcn_s_sleep(1);
        }
        __syncthreads();
    }

    // ---- output: hf + hb (final state is in buffer 0; 800 is even) ----
    if (row_base < BATCH) {   // dir-0 blocks only
        const float* h0 = hbuf;
        #pragma unroll
        for (int j = 0; j < 8; ++j) {
            int idx = j * NTHREADS + tid;          // 0..4095
            int row = row_base + (idx >> 10);      // = b
            int col = idx & 1023;
            float a = ld_agent(h0 + (size_t)row * UNITS + col);
            float c = ld_agent(h0 + (size_t)(row + BATCH) * UNITS + col);
            out[(size_t)row * UNITS + col] = a + c;
        }
    }
}

// ---------------------------------------------------------------------------
extern "C" void kernel_launch(void* const* d_in, const int* in_sizes, int n_in,
                              void* d_out, int out_size, void* d_ws, size_t ws_size,
                              hipStream_t stream) {
    const float* inp  = (const float*)d_in[0];   // [32][800][161]
    const float* W    = (const float*)d_in[1];   // [161][1024]
    const float* U    = (const float*)d_in[2];   // [1024][1024]
    const float* bias = (const float*)d_in[3];   // [1024]
    float* out = (float*)d_out;                  // [32][1024]

    float* Ut     = (float*)d_ws;                         // 1Mi floats
    float* xW     = Ut + (size_t)UNITS * UNITS;           // 26.2M floats
    float* hbuf   = xW + (size_t)T_STEPS * BATCH * UNITS; // 131072 floats
    unsigned* bar = (unsigned*)(hbuf + (size_t)2 * 2 * BATCH * UNITS / 2 * 2);
    bar = (unsigned*)(hbuf + 2 * 2 * BATCH * UNITS);      // after 2 buffers... 
    bar = (unsigned*)(hbuf + (size_t)2 * (2 * BATCH * UNITS));  // hbuf = 2 * 65536 floats

    init_ws<<<64, 256, 0, stream>>>(hbuf, bar);
    transpose_u<<<dim3(32, 32), 256, 0, stream>>>(U, Ut);
    xw_gemm<<<dim3(800, 4), 256, 0, stream>>>(inp, W, bias, xW);

    void* args[] = {(void*)&xW, (void*)&Ut, (void*)&hbuf, (void*)&bar, (void*)&out};
    hipLaunchCooperativeKernel((const void*)rnn_scan, dim3(NBLOCKS), dim3(NTHREADS),
                               args, 0, stream);
}

// Round 3
// 11168.633 us; speedup vs baseline: 4.7496x; 4.1150x over previous
//
#include <hip/hip_runtime.h>

#define T_STEPS  800
#define BATCH    32
#define FEAT     161
#define UNITS    1024
#define CLIPV    20.0f

#define NB       256
#define NT       512
#define ROWS_PB  8            // rows per block (row = dir*32 + b)
#define U_TILE   32           // u columns per block
#define CHUNK    36           // dwords per 32-k chunk (padded, keeps 16B align)
#define ROW_DW   (32 * CHUNK) // 1152 dwords per row in LDS

__device__ __forceinline__ float ld_agent_f(const float* p) {
    return __hip_atomic_load(p, __ATOMIC_RELAXED, __HIP_MEMORY_SCOPE_AGENT);
}
__device__ __forceinline__ unsigned long long ld_agent_u64(const unsigned long long* p) {
    return __hip_atomic_load(p, __ATOMIC_RELAXED, __HIP_MEMORY_SCOPE_AGENT);
}
__device__ __forceinline__ void st_agent_f(float* p, float v) {
    __hip_atomic_store(p, v, __ATOMIC_RELAXED, __HIP_MEMORY_SCOPE_AGENT);
}

// ---------------------------------------------------------------------------
__global__ __launch_bounds__(256) void init_ws(float* hbuf, unsigned* bar) {
    int gid = blockIdx.x * 256 + threadIdx.x;
    for (int i = gid; i < 2 * BATCH * UNITS; i += 64 * 256) hbuf[i] = 0.f;
    if (gid < 576) bar[gid] = 0u;
}

// ---------------------------------------------------------------------------
__global__ __launch_bounds__(256) void transpose_u(const float* __restrict__ U,
                                                   float* __restrict__ Ut) {
    __shared__ float tile[32][33];
    int bx = blockIdx.x, by = blockIdx.y;
    int lx = threadIdx.x & 31;
    int ly4 = (threadIdx.x >> 5) * 4;
    #pragma unroll
    for (int j = 0; j < 4; ++j) {
        int r = by * 32 + ly4 + j;
        tile[ly4 + j][lx] = U[(size_t)r * UNITS + bx * 32 + lx];
    }
    __syncthreads();
    #pragma unroll
    for (int j = 0; j < 4; ++j) {
        int r = bx * 32 + ly4 + j;
        Ut[(size_t)r * UNITS + by * 32 + lx] = tile[lx][ly4 + j];
    }
}

// ---------------------------------------------------------------------------
__global__ __launch_bounds__(256) void xw_gemm(const float* __restrict__ inp,
                                               const float* __restrict__ W,
                                               const float* __restrict__ bias,
                                               float* __restrict__ xW) {
    __shared__ float xs[8 * FEAT];
    int t = blockIdx.x;
    int b0 = blockIdx.y * 8;
    int tid = threadIdx.x;

    for (int i = tid; i < 8 * FEAT; i += 256) {
        int j = i / FEAT;
        int f = i - j * FEAT;
        xs[i] = inp[((size_t)(b0 + j) * T_STEPS + t) * FEAT + f];
    }
    __syncthreads();

    float bv[4];
    #pragma unroll
    for (int c = 0; c < 4; ++c) bv[c] = bias[tid + c * 256];

    float acc[8][4];
    #pragma unroll
    for (int j = 0; j < 8; ++j)
        #pragma unroll
        for (int c = 0; c < 4; ++c) acc[j][c] = bv[c];

    for (int f = 0; f < FEAT; ++f) {
        float w0 = W[(size_t)f * UNITS + tid];
        float w1 = W[(size_t)f * UNITS + tid + 256];
        float w2 = W[(size_t)f * UNITS + tid + 512];
        float w3 = W[(size_t)f * UNITS + tid + 768];
        #pragma unroll
        for (int j = 0; j < 8; ++j) {
            float xv = xs[j * FEAT + f];
            acc[j][0] += xv * w0;
            acc[j][1] += xv * w1;
            acc[j][2] += xv * w2;
            acc[j][3] += xv * w3;
        }
    }

    #pragma unroll
    for (int j = 0; j < 8; ++j)
        #pragma unroll
        for (int c = 0; c < 4; ++c)
            xW[((size_t)t * BATCH + b0 + j) * UNITS + tid + c * 256] = acc[j][c];
}

// ---------------------------------------------------------------------------
// Persistent scan. 256 blocks x 512 threads, 1 block/CU.
// Block (rg 0..7, ug 0..31): rows [rg*8, rg*8+8), u [ug*32, ug*32+32).
// Thread (up 0..15, kc 0..31): u pair {u0, u0+1}, k slice [kc*32, kc*32+32),
// all 8 rows. ufr = 16 float4 = 64 VGPRs (fits; no spill).
// h staged to padded LDS each step (agent-scope 8B loads); k-reduction via
// shfl_xor over the 32 kc lanes; kc==0 lanes add xW, clip, store agent-scope.
__global__ __launch_bounds__(NT, 2) void rnn_scan(
        const float* __restrict__ xW, const float* __restrict__ Ut,
        float* __restrict__ hbuf, unsigned* __restrict__ bar,
        float* __restrict__ out) {
    __shared__ float h_lds[ROWS_PB * ROW_DW];   // 36 KB

    const int tid = threadIdx.x;
    const int bk  = blockIdx.x;
    const int kc  = tid & 31;
    const int up  = tid >> 5;
    const int ug  = bk & 31;
    const int rg  = bk >> 5;
    const int row_base = rg * ROWS_PB;
    const int u0  = ug * U_TILE + up * 2;
    const int dir = row_base >> 5;              // uniform per block (8 | 32)

    // --- U fragment: Ut[u0+j][kc*32 .. +32), j=0,1 -> 16 float4 = 64 VGPRs ---
    float4 ufr[2][8];
    #pragma unroll
    for (int j = 0; j < 2; ++j) {
        const float4* us = (const float4*)(Ut + (size_t)(u0 + j) * UNITS + kc * 32);
        #pragma unroll
        for (int i = 0; i < 8; ++i) ufr[j][i] = us[i];
    }

    const size_t HS = (size_t)2 * BATCH * UNITS;
    unsigned* leaf = bar + (bk & 15) * 32;
    unsigned* root = bar + 512;
    unsigned* gen  = bar + 544;

    for (int t = 0; t < T_STEPS; ++t) {
        // ---- stage 8 h rows into padded LDS (coalesced 8B agent loads) ----
        const unsigned long long* hsrc = (const unsigned long long*)
            (hbuf + (size_t)(t & 1) * HS + (size_t)row_base * UNITS);
        #pragma unroll
        for (int j = 0; j < 8; ++j) {
            int ui = j * NT + tid;               // 0..4095 ull index
            unsigned long long v = ld_agent_u64(hsrc + ui);
            int r  = ui >> 9;                    // 512 ull per row
            int kd = (ui & 511) << 1;            // dword offset in row
            *(unsigned long long*)
                &h_lds[r * ROW_DW + (kd >> 5) * CHUNK + (kd & 31)] = v;
        }
        __syncthreads();

        // ---- dot products: 8 rows x 2 u x 32 k; each b128 feeds 8 FMAs ----
        float acc[8][2];
        #pragma unroll
        for (int r = 0; r < 8; ++r) acc[r][0] = acc[r][1] = 0.f;
        const float* hb = h_lds + kc * CHUNK;
        #pragma unroll
        for (int i = 0; i < 8; ++i) {
            #pragma unroll
            for (int r = 0; r < 8; ++r) {
                float4 h4 = *(const float4*)(hb + r * ROW_DW + i * 4);
                acc[r][0] = fmaf(h4.x, ufr[0][i].x, fmaf(h4.y, ufr[0][i].y,
                            fmaf(h4.z, ufr[0][i].z, fmaf(h4.w, ufr[0][i].w, acc[r][0]))));
                acc[r][1] = fmaf(h4.x, ufr[1][i].x, fmaf(h4.y, ufr[1][i].y,
                            fmaf(h4.z, ufr[1][i].z, fmaf(h4.w, ufr[1][i].w, acc[r][1]))));
            }
        }

        // ---- reduce over the 32 kc lanes (butterfly within 32-lane halves) ----
        #pragma unroll
        for (int m = 1; m <= 16; m <<= 1) {
            #pragma unroll
            for (int r = 0; r < 8; ++r) {
                acc[r][0] += __shfl_xor(acc[r][0], m, 32);
                acc[r][1] += __shfl_xor(acc[r][1], m, 32);
            }
        }

        // ---- kc==0: add xW (loaded late to keep regs free), clip, store ----
        if (kc == 0) {
            const int xt = dir ? (T_STEPS - 1 - t) : t;
            float* hdst = hbuf + (size_t)((t & 1) ^ 1) * HS;
            #pragma unroll
            for (int r = 0; r < 8; ++r) {
                int b = (row_base + r) & 31;
                #pragma unroll
                for (int j = 0; j < 2; ++j) {
                    float x = xW[(size_t)xt * (BATCH * UNITS) + b * UNITS + u0 + j];
                    float a = fminf(fmaxf(acc[r][j] + x, 0.f), CLIPV);
                    st_agent_f(hdst + (size_t)(row_base + r) * UNITS + u0 + j, a);
                }
            }
        }
        __syncthreads();   // protects h_lds for restage; drains store vmcnt

        // ---- two-level monotone grid barrier ----
        if (tid == 0) {
            unsigned tgt = 16u * (unsigned)(t + 1);
            unsigned old = __hip_atomic_fetch_add(leaf, 1u, __ATOMIC_RELAXED,
                                                  __HIP_MEMORY_SCOPE_AGENT);
            if (old == tgt - 1u) {
                unsigned rold = __hip_atomic_fetch_add(root, 1u, __ATOMIC_RELAXED,
                                                       __HIP_MEMORY_SCOPE_AGENT);
                if (rold == tgt - 1u)
                    __hip_atomic_store(gen, (unsigned)(t + 1), __ATOMIC_RELAXED,
                                       __HIP_MEMORY_SCOPE_AGENT);
            }
            while (__hip_atomic_load(gen, __ATOMIC_RELAXED,
                                     __HIP_MEMORY_SCOPE_AGENT) < (unsigned)(t + 1))
                __builtin_amdgcn_s_sleep(1);
        }
        __syncthreads();
    }

    // ---- epilogue: out = hf + hb (final state in buffer 0; 800 even) ----
    if (ug == 0 && row_base < BATCH) {
        #pragma unroll
        for (int j = 0; j < 16; ++j) {
            int idx = j * NT + tid;              // 0..8191
            int b   = row_base + (idx >> 10);
            int col = idx & 1023;
            float a = ld_agent_f(hbuf + (size_t)b * UNITS + col);
            float c = ld_agent_f(hbuf + (size_t)(b + BATCH) * UNITS + col);
            out[(size_t)b * UNITS + col] = a + c;
        }
    }
}

// ---------------------------------------------------------------------------
extern "C" void kernel_launch(void* const* d_in, const int* in_sizes, int n_in,
                              void* d_out, int out_size, void* d_ws, size_t ws_size,
                              hipStream_t stream) {
    const float* inp  = (const float*)d_in[0];   // [32][800][161]
    const float* W    = (const float*)d_in[1];   // [161][1024]
    const float* U    = (const float*)d_in[2];   // [1024][1024]
    const float* bias = (const float*)d_in[3];   // [1024]
    float* out = (float*)d_out;                  // [32][1024]

    float* Ut     = (float*)d_ws;                          // 1Mi floats
    float* xW     = Ut + (size_t)UNITS * UNITS;            // 26.2M floats
    float* hbuf   = xW + (size_t)T_STEPS * BATCH * UNITS;  // 2 x 65536 floats
    unsigned* bar = (unsigned*)(hbuf + (size_t)2 * (2 * BATCH * UNITS));

    init_ws<<<64, 256, 0, stream>>>(hbuf, bar);
    transpose_u<<<dim3(32, 32), 256, 0, stream>>>(U, Ut);
    xw_gemm<<<dim3(800, 4), 256, 0, stream>>>(inp, W, bias, xW);

    void* args[] = {(void*)&xW, (void*)&Ut, (void*)&hbuf, (void*)&bar, (void*)&out};
    hipLaunchCooperativeKernel((const void*)rnn_scan, dim3(NB), dim3(NT),
                               args, 0, stream);
}

// Round 4
// 5945.836 us; speedup vs baseline: 8.9216x; 1.8784x over previous
//
#include <hip/hip_runtime.h>
#include <hip/hip_bf16.h>

#define T_STEPS 800
#define BATCH   32
#define FEAT    161
#define UNITS   1024
#define CLIPV   20.0f

typedef __attribute__((ext_vector_type(8))) short short8;
typedef __attribute__((ext_vector_type(4))) float f32x4;
typedef unsigned short u16;
typedef unsigned long long u64;

__device__ __forceinline__ u16 bf16_rn(float x) {
    __hip_bfloat16 b = __float2bfloat16(x);
    return *(u16*)&b;
}
__device__ __forceinline__ float bf16_f(u16 u) {
    __hip_bfloat16 b;
    *(u16*)&b = u;
    return __bfloat162float(b);
}
__device__ __forceinline__ u64 ld_agent_u64(const u64* p) {
    return __hip_atomic_load(p, __ATOMIC_RELAXED, __HIP_MEMORY_SCOPE_AGENT);
}
__device__ __forceinline__ u16 ld_agent_u16(const u16* p) {
    return __hip_atomic_load(p, __ATOMIC_RELAXED, __HIP_MEMORY_SCOPE_AGENT);
}
__device__ __forceinline__ void st_agent_u16(u16* p, u16 v) {
    __hip_atomic_store(p, v, __ATOMIC_RELAXED, __HIP_MEMORY_SCOPE_AGENT);
}
__device__ __forceinline__ short8 ld_agent_b16x8(const u16* p) {
    union { u64 q[2]; short8 v; } u;
    u.q[0] = ld_agent_u64((const u64*)p);
    u.q[1] = ld_agent_u64((const u64*)p + 1);
    return u.v;
}

// ---------------------------------------------------------------------------
// zero the h split planes (3 x 2 x 64 x 1024 u16, contiguous) + barrier words
__global__ __launch_bounds__(256) void init_ws(unsigned* hz, unsigned* bar) {
    int gid = blockIdx.x * 256 + threadIdx.x;             // 24576 threads
    for (int i = gid; i < 196608; i += 96 * 256) hz[i] = 0u;
    if (gid < 2048) bar[gid] = 0u;
}

// ---------------------------------------------------------------------------
// Ut splits: U[k][u] fp32 -> Ut1/2/3[u][k] bf16 (hi / mid / lo, 24-bit total)
__global__ __launch_bounds__(256) void u_split_t(const float* __restrict__ U,
                                                 u16* __restrict__ Ut1,
                                                 u16* __restrict__ Ut2,
                                                 u16* __restrict__ Ut3) {
    __shared__ float tile[32][33];
    int bx = blockIdx.x, by = blockIdx.y;
    int lx = threadIdx.x & 31;
    int ly4 = (threadIdx.x >> 5) * 4;
    #pragma unroll
    for (int j = 0; j < 4; ++j)
        tile[ly4 + j][lx] = U[(size_t)(by * 32 + ly4 + j) * UNITS + bx * 32 + lx];
    __syncthreads();
    #pragma unroll
    for (int j = 0; j < 4; ++j) {
        float x = tile[lx][ly4 + j];                     // = U[by*32+lx][bx*32+ly4+j]
        size_t o = (size_t)(bx * 32 + ly4 + j) * UNITS + by * 32 + lx;  // Ut[u][k]
        u16 s1 = bf16_rn(x);  float r1 = x - bf16_f(s1);
        u16 s2 = bf16_rn(r1); float r2 = r1 - bf16_f(s2);
        u16 s3 = bf16_rn(r2);
        Ut1[o] = s1; Ut2[o] = s2; Ut3[o] = s3;
    }
}

// ---------------------------------------------------------------------------
__global__ __launch_bounds__(256) void xw_gemm(const float* __restrict__ inp,
                                               const float* __restrict__ W,
                                               const float* __restrict__ bias,
                                               float* __restrict__ xW) {
    __shared__ float xs[8 * FEAT];
    int t = blockIdx.x;
    int b0 = blockIdx.y * 8;
    int tid = threadIdx.x;

    for (int i = tid; i < 8 * FEAT; i += 256) {
        int j = i / FEAT;
        int f = i - j * FEAT;
        xs[i] = inp[((size_t)(b0 + j) * T_STEPS + t) * FEAT + f];
    }
    __syncthreads();

    float bv[4];
    #pragma unroll
    for (int c = 0; c < 4; ++c) bv[c] = bias[tid + c * 256];

    float acc[8][4];
    #pragma unroll
    for (int j = 0; j < 8; ++j)
        #pragma unroll
        for (int c = 0; c < 4; ++c) acc[j][c] = bv[c];

    for (int f = 0; f < FEAT; ++f) {
        float w0 = W[(size_t)f * UNITS + tid];
        float w1 = W[(size_t)f * UNITS + tid + 256];
        float w2 = W[(size_t)f * UNITS + tid + 512];
        float w3 = W[(size_t)f * UNITS + tid + 768];
        #pragma unroll
        for (int j = 0; j < 8; ++j) {
            float xv = xs[j * FEAT + f];
            acc[j][0] += xv * w0;
            acc[j][1] += xv * w1;
            acc[j][2] += xv * w2;
            acc[j][3] += xv * w3;
        }
    }

    #pragma unroll
    for (int j = 0; j < 8; ++j)
        #pragma unroll
        for (int c = 0; c < 4; ++c)
            xW[((size_t)t * BATCH + b0 + j) * UNITS + tid + c * 256] = acc[j][c];
}

// ---------------------------------------------------------------------------
// MFMA recurrent scan. 128 blocks x 512 threads (8 waves).
// Block (rg 0..3, ug 0..31): rows [rg*16,+16) (row = dir*32 + b), u [ug*32,+32).
// Wave kq (0..7): k-slice [kq*128,+128) = 4 MFMA k-steps. Each wave computes
// partial C[16 rows][32 u] (two 16x16 n-tiles) via 48 mfma_f32_16x16x32_bf16:
// fp32-equivalent split products h1u1,h1u2,h2u1,h2u2,h1u3,h3u1.
// U splits live in 96 VGPRs/wave (loaded once). A-fragments read directly
// from the global h split planes at agent scope (no LDS staging).
// Sync: 4 independent per-row-group barriers (32 blocks each) — forward and
// backward directions fully decoupled. Per-wave gen polling (no extra
// __syncthreads on the wake path).
__global__ __launch_bounds__(512, 2) void rnn_scan(
        const float* __restrict__ xW,
        const u16* __restrict__ Ut1, const u16* __restrict__ Ut2,
        const u16* __restrict__ Ut3,
        u16* __restrict__ H1, u16* __restrict__ H2, u16* __restrict__ H3,
        unsigned* __restrict__ bar, float* __restrict__ out) {
    __shared__ f32x4 red[14][64];   // 14 KB cross-wave C partials

    const int tid  = threadIdx.x;
    const int bk   = blockIdx.x;
    const int lane = tid & 63;
    const int kq   = tid >> 6;       // 0..7
    const int quad = lane >> 4;      // 0..3
    const int n16  = lane & 15;      // A: m-row, B: n-col, C: col
    const int rg   = bk & 3;
    const int ug   = bk >> 2;
    const int R0   = rg * 16;
    const int u0   = ug * 32;
    const int dir  = rg >> 1;

    // --- B fragments: U splits for this wave's k-slice, both n-tiles ---
    short8 bfr[4][2][3];
    #pragma unroll
    for (int ks = 0; ks < 4; ++ks) {
        const int koff = kq * 128 + ks * 32 + quad * 8;
        #pragma unroll
        for (int nq = 0; nq < 2; ++nq) {
            const size_t ub = (size_t)(u0 + nq * 16 + n16) * UNITS + koff;
            bfr[ks][nq][0] = *(const short8*)(Ut1 + ub);
            bfr[ks][nq][1] = *(const short8*)(Ut2 + ub);
            bfr[ks][nq][2] = *(const short8*)(Ut3 + ub);
        }
    }

    const size_t HSZ = (size_t)64 * UNITS;       // one h buffer (u16 elems)
    unsigned* cnt = bar + rg * 64;
    unsigned* gen = bar + rg * 64 + 32;

    for (int t = 0; t < T_STEPS; ++t) {
        const size_t sb = (size_t)(t & 1) * HSZ;
        const size_t db = (size_t)((t & 1) ^ 1) * HSZ;

        // xW prefetch (combining wave only; issued early to hide latency)
        float xp[2][4];
        if (kq == 0) {
            const int xt = dir ? (T_STEPS - 1 - t) : t;
            #pragma unroll
            for (int nq = 0; nq < 2; ++nq)
                #pragma unroll
                for (int j = 0; j < 4; ++j) {
                    const int b = (R0 + quad * 4 + j) & 31;
                    xp[nq][j] = xW[(size_t)xt * (BATCH * UNITS) +
                                   (size_t)b * UNITS + u0 + nq * 16 + n16];
                }
        }

        // --- A loads (agent scope, 16B/lane = full 64B lines per quad) + MFMA
        f32x4 acc[2][2] = {{{0.f,0.f,0.f,0.f},{0.f,0.f,0.f,0.f}},
                           {{0.f,0.f,0.f,0.f},{0.f,0.f,0.f,0.f}}};
        #pragma unroll
        for (int ks = 0; ks < 4; ++ks) {
            const size_t ab = sb + (size_t)(R0 + n16) * UNITS +
                              kq * 128 + ks * 32 + quad * 8;
            short8 a1 = ld_agent_b16x8(H1 + ab);
            short8 a2 = ld_agent_b16x8(H2 + ab);
            short8 a3 = ld_agent_b16x8(H3 + ab);
            #pragma unroll
            for (int nq = 0; nq < 2; ++nq) {
                acc[nq][0] = __builtin_amdgcn_mfma_f32_16x16x32_bf16(a1, bfr[ks][nq][0], acc[nq][0], 0, 0, 0);
                acc[nq][1] = __builtin_amdgcn_mfma_f32_16x16x32_bf16(a2, bfr[ks][nq][0], acc[nq][1], 0, 0, 0);
                acc[nq][0] = __builtin_amdgcn_mfma_f32_16x16x32_bf16(a1, bfr[ks][nq][1], acc[nq][0], 0, 0, 0);
                acc[nq][1] = __builtin_amdgcn_mfma_f32_16x16x32_bf16(a2, bfr[ks][nq][1], acc[nq][1], 0, 0, 0);
                acc[nq][0] = __builtin_amdgcn_mfma_f32_16x16x32_bf16(a1, bfr[ks][nq][2], acc[nq][0], 0, 0, 0);
                acc[nq][1] = __builtin_amdgcn_mfma_f32_16x16x32_bf16(a3, bfr[ks][nq][0], acc[nq][1], 0, 0, 0);
            }
        }
        f32x4 c0 = acc[0][0] + acc[0][1];
        f32x4 c1 = acc[1][0] + acc[1][1];

        // --- cross-wave k-reduction through LDS ---
        if (kq) {
            red[(kq - 1) * 2 + 0][lane] = c0;
            red[(kq - 1) * 2 + 1][lane] = c1;
        }
        __syncthreads();
        if (kq == 0) {
            #pragma unroll
            for (int w = 0; w < 7; ++w) {
                c0 += red[w * 2 + 0][lane];
                c1 += red[w * 2 + 1][lane];
            }
            // epilogue: add xW, relu-clip, split to 3 bf16 planes, agent store
            #pragma unroll
            for (int nq = 0; nq < 2; ++nq) {
                #pragma unroll
                for (int j = 0; j < 4; ++j) {
                    float a = (nq ? c1[j] : c0[j]) + xp[nq][j];
                    a = fminf(fmaxf(a, 0.f), CLIPV);
                    u16 s1 = bf16_rn(a);  float r1 = a - bf16_f(s1);
                    u16 s2 = bf16_rn(r1); float r2 = r1 - bf16_f(s2);
                    u16 s3 = bf16_rn(r2);
                    const size_t off = db + (size_t)(R0 + quad * 4 + j) * UNITS +
                                       u0 + nq * 16 + n16;
                    st_agent_u16(H1 + off, s1);
                    st_agent_u16(H2 + off, s2);
                    st_agent_u16(H3 + off, s3);
                }
            }
        }
        __syncthreads();   // drains kq0's agent stores (vmcnt 0) before arrive

        // --- per-row-group barrier (32 blocks), monotone, per-wave polling ---
        if (tid == 0) {
            unsigned old = __hip_atomic_fetch_add(cnt, 1u, __ATOMIC_RELAXED,
                                                  __HIP_MEMORY_SCOPE_AGENT);
            if (old == 32u * (unsigned)(t + 1) - 1u)
                __hip_atomic_store(gen, (unsigned)(t + 1), __ATOMIC_RELAXED,
                                   __HIP_MEMORY_SCOPE_AGENT);
        }
        while (__hip_atomic_load(gen, __ATOMIC_RELAXED,
                                 __HIP_MEMORY_SCOPE_AGENT) < (unsigned)(t + 1))
            __builtin_amdgcn_s_sleep(1);
    }

    // --- global barrier (all 4 groups), then out = hf + hb ---
    if (tid == 0) {
        unsigned old = __hip_atomic_fetch_add(bar + 512, 1u, __ATOMIC_RELAXED,
                                              __HIP_MEMORY_SCOPE_AGENT);
        if (old == 127u)
            __hip_atomic_store(bar + 544, 1u, __ATOMIC_RELAXED,
                               __HIP_MEMORY_SCOPE_AGENT);
    }
    if (rg < 2) {   // forward groups write the output
        while (__hip_atomic_load(bar + 544, __ATOMIC_RELAXED,
                                 __HIP_MEMORY_SCOPE_AGENT) < 1u)
            __builtin_amdgcn_s_sleep(1);
        const int r_l = tid >> 5, uu = tid & 31;
        const int b = R0 + r_l;                       // 0..31
        const size_t o1 = (size_t)b * UNITS + u0 + uu;          // fwd row, buf 0
        const size_t o2 = (size_t)(b + 32) * UNITS + u0 + uu;   // bwd row, buf 0
        float hf = bf16_f(ld_agent_u16(H1 + o1)) + bf16_f(ld_agent_u16(H2 + o1))
                 + bf16_f(ld_agent_u16(H3 + o1));
        float hb = bf16_f(ld_agent_u16(H1 + o2)) + bf16_f(ld_agent_u16(H2 + o2))
                 + bf16_f(ld_agent_u16(H3 + o2));
        out[(size_t)b * UNITS + u0 + uu] = hf + hb;
    }
}

// ---------------------------------------------------------------------------
extern "C" void kernel_launch(void* const* d_in, const int* in_sizes, int n_in,
                              void* d_out, int out_size, void* d_ws, size_t ws_size,
                              hipStream_t stream) {
    const float* inp  = (const float*)d_in[0];   // [32][800][161]
    const float* W    = (const float*)d_in[1];   // [161][1024]
    const float* U    = (const float*)d_in[2];   // [1024][1024]
    const float* bias = (const float*)d_in[3];   // [1024]
    float* out = (float*)d_out;                  // [32][1024]

    u16*   Ut1 = (u16*)d_ws;                              // 3 x 2 MB bf16 planes
    u16*   Ut2 = Ut1 + (size_t)UNITS * UNITS;
    u16*   Ut3 = Ut2 + (size_t)UNITS * UNITS;
    float* xW  = (float*)(Ut3 + (size_t)UNITS * UNITS);   // 104.9 MB
    u16*   H1  = (u16*)(xW + (size_t)T_STEPS * BATCH * UNITS);  // 3 x 256 KB
    u16*   H2  = H1 + (size_t)2 * 64 * UNITS;
    u16*   H3  = H2 + (size_t)2 * 64 * UNITS;
    unsigned* bar = (unsigned*)(H3 + (size_t)2 * 64 * UNITS);

    init_ws<<<96, 256, 0, stream>>>((unsigned*)H1, bar);
    u_split_t<<<dim3(32, 32), 256, 0, stream>>>(U, Ut1, Ut2, Ut3);
    xw_gemm<<<dim3(800, 4), 256, 0, stream>>>(inp, W, bias, xW);

    void* args[] = {(void*)&xW, (void*)&Ut1, (void*)&Ut2, (void*)&Ut3,
                    (void*)&H1, (void*)&H2, (void*)&H3, (void*)&bar, (void*)&out};
    hipLaunchCooperativeKernel((const void*)rnn_scan, dim3(128), dim3(512),
                               args, 0, stream);
}

// Round 5
// 4331.866 us; speedup vs baseline: 12.2456x; 1.3726x over previous
//
#include <hip/hip_runtime.h>
#include <hip/hip_bf16.h>

#define T_STEPS 800
#define BATCH   32
#define FEAT    161
#define UNITS   1024
#define CLIPV   20.0f

typedef __attribute__((ext_vector_type(8))) short short8;
typedef __attribute__((ext_vector_type(4))) float f32x4;
typedef unsigned short u16;
typedef unsigned int   u32;
typedef unsigned long long u64;

__device__ __forceinline__ float bf16_f(u16 u) {
    return __uint_as_float(((u32)u) << 16);
}
__device__ __forceinline__ u16 bf16_rn(float x) {
    __hip_bfloat16 b = __float2bfloat16(x);
    return *(u16*)&b;
}
__device__ __forceinline__ u64 ld_agent_u64(const u64* p) {
    return __hip_atomic_load(p, __ATOMIC_RELAXED, __HIP_MEMORY_SCOPE_AGENT);
}
__device__ __forceinline__ float ld_agent_f(const float* p) {
    return __hip_atomic_load(p, __ATOMIC_RELAXED, __HIP_MEMORY_SCOPE_AGENT);
}
__device__ __forceinline__ void st_agent_f(float* p, float v) {
    __hip_atomic_store(p, v, __ATOMIC_RELAXED, __HIP_MEMORY_SCOPE_AGENT);
}
__device__ __forceinline__ void st_agent_u32(u32* p, u32 v) {
    __hip_atomic_store(p, v, __ATOMIC_RELAXED, __HIP_MEMORY_SCOPE_AGENT);
}
__device__ __forceinline__ short8 ld_agent_b16x8(const u16* p) {
    union { u64 q[2]; short8 v; } u;
    u.q[0] = ld_agent_u64((const u64*)p);
    u.q[1] = ld_agent_u64((const u64*)p + 1);
    return u.v;
}

// ---------------------------------------------------------------------------
// zero h double-buffer (2 x 64 x 1024 fp32) + flags
__global__ __launch_bounds__(256) void init_ws(float* hbuf, u32* flags) {
    int gid = blockIdx.x * 256 + threadIdx.x;         // 16384 threads
    for (int i = gid; i < 2 * 64 * UNITS; i += 64 * 256) hbuf[i] = 0.f;
    if (gid < 256) flags[gid] = 0u;
}

// ---------------------------------------------------------------------------
// Ut splits: U[k][u] fp32 -> Ut1/2/3[u][k] bf16 (hi/mid/lo, 24-bit total)
__global__ __launch_bounds__(256) void u_split_t(const float* __restrict__ U,
                                                 u16* __restrict__ Ut1,
                                                 u16* __restrict__ Ut2,
                                                 u16* __restrict__ Ut3) {
    __shared__ float tile[32][33];
    int bx = blockIdx.x, by = blockIdx.y;
    int lx = threadIdx.x & 31;
    int ly4 = (threadIdx.x >> 5) * 4;
    #pragma unroll
    for (int j = 0; j < 4; ++j)
        tile[ly4 + j][lx] = U[(size_t)(by * 32 + ly4 + j) * UNITS + bx * 32 + lx];
    __syncthreads();
    #pragma unroll
    for (int j = 0; j < 4; ++j) {
        float x = tile[lx][ly4 + j];
        size_t o = (size_t)(bx * 32 + ly4 + j) * UNITS + by * 32 + lx;
        u16 s1 = bf16_rn(x);  float r1 = x - bf16_f(s1);
        u16 s2 = bf16_rn(r1); float r2 = r1 - bf16_f(s2);
        u16 s3 = bf16_rn(r2);
        Ut1[o] = s1; Ut2[o] = s2; Ut3[o] = s3;
    }
}

// ---------------------------------------------------------------------------
__global__ __launch_bounds__(256) void xw_gemm(const float* __restrict__ inp,
                                               const float* __restrict__ W,
                                               const float* __restrict__ bias,
                                               float* __restrict__ xW) {
    __shared__ float xs[8 * FEAT];
    int t = blockIdx.x;
    int b0 = blockIdx.y * 8;
    int tid = threadIdx.x;

    for (int i = tid; i < 8 * FEAT; i += 256) {
        int j = i / FEAT;
        int f = i - j * FEAT;
        xs[i] = inp[((size_t)(b0 + j) * T_STEPS + t) * FEAT + f];
    }
    __syncthreads();

    float bv[4];
    #pragma unroll
    for (int c = 0; c < 4; ++c) bv[c] = bias[tid + c * 256];

    float acc[8][4];
    #pragma unroll
    for (int j = 0; j < 8; ++j)
        #pragma unroll
        for (int c = 0; c < 4; ++c) acc[j][c] = bv[c];

    for (int f = 0; f < FEAT; ++f) {
        float w0 = W[(size_t)f * UNITS + tid];
        float w1 = W[(size_t)f * UNITS + tid + 256];
        float w2 = W[(size_t)f * UNITS + tid + 512];
        float w3 = W[(size_t)f * UNITS + tid + 768];
        #pragma unroll
        for (int j = 0; j < 8; ++j) {
            float xv = xs[j * FEAT + f];
            acc[j][0] += xv * w0;
            acc[j][1] += xv * w1;
            acc[j][2] += xv * w2;
            acc[j][3] += xv * w3;
        }
    }

    #pragma unroll
    for (int j = 0; j < 8; ++j)
        #pragma unroll
        for (int c = 0; c < 4; ++c)
            xW[((size_t)t * BATCH + b0 + j) * UNITS + tid + c * 256] = acc[j][c];
}

// ---------------------------------------------------------------------------
// Dataflow MFMA scan. 128 blocks x 512 threads.
// Block (rg 0..3, ug 0..31): rows [rg*16,+16) (row = dir*32+b), cols [ug*32,+32).
// Wave kq: k-slice [kq*128,+128); its 4 source slices are written by blocks
// (rg, 4kq..4kq+3). Sync = per-writer monotone flags only — NO barrier:
// writer stores fp32 slice -> __syncthreads (drains vmcnt) -> flag = t+1;
// reader wave polls its 4 flags (one 16B load) >= t. WAR-safe with 2 buffers
// because a writer reaching step t+1 implies all blocks stored step t, which
// implies all step-t loads are complete (loads precede each block's store).
// h exchanged as fp32; reader splits to 3 bf16 planes in VALU (24-bit exact).
__global__ __launch_bounds__(512) void rnn_scan(
        const float* __restrict__ xW,
        const u16* __restrict__ Ut1, const u16* __restrict__ Ut2,
        const u16* __restrict__ Ut3,
        float* __restrict__ hbuf, u32* __restrict__ flags,
        float* __restrict__ out) {
    __shared__ f32x4 red[14][64];   // 14 KB cross-wave C partials

    const int tid  = threadIdx.x;
    const int bk   = blockIdx.x;
    const int lane = tid & 63;
    const int kq   = tid >> 6;       // 0..7
    const int quad = lane >> 4;      // 0..3
    const int n16  = lane & 15;
    const int rg   = bk & 3;
    const int ug   = bk >> 2;
    const int R0   = rg * 16;
    const int u0   = ug * 32;
    const int dir  = rg >> 1;

    // --- B fragments (atomic loads -> not rematerializable -> stay in regs) ---
    short8 bfr[4][2][3];
    #pragma unroll
    for (int ks = 0; ks < 4; ++ks) {
        const int koff = kq * 128 + ks * 32 + quad * 8;
        #pragma unroll
        for (int nq = 0; nq < 2; ++nq) {
            const size_t ub = (size_t)(u0 + nq * 16 + n16) * UNITS + koff;
            bfr[ks][nq][0] = ld_agent_b16x8(Ut1 + ub);
            bfr[ks][nq][1] = ld_agent_b16x8(Ut2 + ub);
            bfr[ks][nq][2] = ld_agent_b16x8(Ut3 + ub);
        }
    }

    const size_t HS = (size_t)64 * UNITS;            // fp32 elems per buffer
    u32* myflag = flags + rg * 32 + ug;
    const u64* srcflag = (const u64*)(flags + rg * 32 + kq * 4);

    for (int t = 0; t < T_STEPS; ++t) {
        const size_t sb = (size_t)(t & 1) * HS;
        const size_t db = sb ^ HS;

        // xW prefetch (combining wave only)
        float xp[2][4];
        if (kq == 0) {
            const int xt = dir ? (T_STEPS - 1 - t) : t;
            #pragma unroll
            for (int nq = 0; nq < 2; ++nq)
                #pragma unroll
                for (int j = 0; j < 4; ++j) {
                    const int b = (R0 + quad * 4 + j) & 31;
                    xp[nq][j] = xW[(size_t)xt * (BATCH * UNITS) +
                                   (size_t)b * UNITS + u0 + nq * 16 + n16];
                }
        }

        // ---- wait for this wave's 4 source slices (one 16B poll load) ----
        const u32 tgt = (u32)t;
        for (;;) {
            u64 qa = ld_agent_u64(srcflag);
            u64 qb = ld_agent_u64(srcflag + 1);
            u32 f0 = (u32)qa, f1 = (u32)(qa >> 32);
            u32 f2 = (u32)qb, f3 = (u32)(qb >> 32);
            if (f0 >= tgt && f1 >= tgt && f2 >= tgt && f3 >= tgt) break;
        }

        // ---- load fp32 h, split to 3 bf16 planes, MFMA ----
        f32x4 acc[2][2] = {{{0.f,0.f,0.f,0.f},{0.f,0.f,0.f,0.f}},
                           {{0.f,0.f,0.f,0.f},{0.f,0.f,0.f,0.f}}};
        #pragma unroll
        for (int ks = 0; ks < 4; ++ks) {
            const float* ap = hbuf + sb + (size_t)(R0 + n16) * UNITS +
                              kq * 128 + ks * 32 + quad * 8;
            union { u64 q[4]; float f[8]; u32 u[8]; } hv;
            hv.q[0] = ld_agent_u64((const u64*)ap);
            hv.q[1] = ld_agent_u64((const u64*)ap + 1);
            hv.q[2] = ld_agent_u64((const u64*)ap + 2);
            hv.q[3] = ld_agent_u64((const u64*)ap + 3);
            short8 a1, a2, a3;
            #pragma unroll
            for (int j = 0; j < 8; ++j) {
                float x = hv.f[j];
                u16 s1 = (u16)(hv.u[j] >> 16);          // bf16 truncation (exact residual)
                float r1 = x - bf16_f(s1);
                u16 s2 = (u16)(__float_as_uint(r1) >> 16);
                float r2 = r1 - bf16_f(s2);
                u16 s3 = (u16)(__float_as_uint(r2) >> 16);
                a1[j] = (short)s1; a2[j] = (short)s2; a3[j] = (short)s3;
            }
            #pragma unroll
            for (int nq = 0; nq < 2; ++nq) {
                acc[nq][0] = __builtin_amdgcn_mfma_f32_16x16x32_bf16(a1, bfr[ks][nq][0], acc[nq][0], 0, 0, 0);
                acc[nq][1] = __builtin_amdgcn_mfma_f32_16x16x32_bf16(a2, bfr[ks][nq][0], acc[nq][1], 0, 0, 0);
                acc[nq][0] = __builtin_amdgcn_mfma_f32_16x16x32_bf16(a1, bfr[ks][nq][1], acc[nq][0], 0, 0, 0);
                acc[nq][1] = __builtin_amdgcn_mfma_f32_16x16x32_bf16(a2, bfr[ks][nq][1], acc[nq][1], 0, 0, 0);
                acc[nq][0] = __builtin_amdgcn_mfma_f32_16x16x32_bf16(a1, bfr[ks][nq][2], acc[nq][0], 0, 0, 0);
                acc[nq][1] = __builtin_amdgcn_mfma_f32_16x16x32_bf16(a3, bfr[ks][nq][0], acc[nq][1], 0, 0, 0);
            }
        }
        f32x4 c0 = acc[0][0] + acc[0][1];
        f32x4 c1 = acc[1][0] + acc[1][1];

        // ---- cross-wave k-reduction through LDS ----
        if (kq) {
            red[(kq - 1) * 2 + 0][lane] = c0;
            red[(kq - 1) * 2 + 1][lane] = c1;
        }
        __syncthreads();
        if (kq == 0) {
            #pragma unroll
            for (int w = 0; w < 7; ++w) {
                c0 += red[w * 2 + 0][lane];
                c1 += red[w * 2 + 1][lane];
            }
            float* hdst = hbuf + db;
            #pragma unroll
            for (int nq = 0; nq < 2; ++nq)
                #pragma unroll
                for (int j = 0; j < 4; ++j) {
                    float a = (nq ? c1[j] : c0[j]) + xp[nq][j];
                    a = fminf(fmaxf(a, 0.f), CLIPV);
                    st_agent_f(hdst + (size_t)(R0 + quad * 4 + j) * UNITS +
                               u0 + nq * 16 + n16, a);
                }
        }
        // barrier: (a) protects red[] for next step, (b) compiler emits
        // s_waitcnt vmcnt(0) per wave before s_barrier -> kq0's slice stores
        // are acked at the coherence point before the flag is published.
        __syncthreads();
        if (tid == 0) st_agent_u32(myflag, (u32)(t + 1));
    }

    // ---- epilogue: out = hf + hb (final state in buffer 0; 800 even) ----
    if (rg < 2) {
        // own fwd slice is done (this block wrote it); wait for bwd partner
        const u32* bwd = flags + (rg + 2) * 32 + ug;
        while (__hip_atomic_load(bwd, __ATOMIC_RELAXED,
                                 __HIP_MEMORY_SCOPE_AGENT) < (u32)T_STEPS) {}
        const int r = tid >> 5, c = tid & 31;
        const int b = R0 + r;
        float hf = ld_agent_f(hbuf + (size_t)b * UNITS + u0 + c);
        float hb = ld_agent_f(hbuf + (size_t)(b + 32) * UNITS + u0 + c);
        out[(size_t)b * UNITS + u0 + c] = hf + hb;
    }
}

// ---------------------------------------------------------------------------
extern "C" void kernel_launch(void* const* d_in, const int* in_sizes, int n_in,
                              void* d_out, int out_size, void* d_ws, size_t ws_size,
                              hipStream_t stream) {
    const float* inp  = (const float*)d_in[0];   // [32][800][161]
    const float* W    = (const float*)d_in[1];   // [161][1024]
    const float* U    = (const float*)d_in[2];   // [1024][1024]
    const float* bias = (const float*)d_in[3];   // [1024]
    float* out = (float*)d_out;                  // [32][1024]

    u16*   Ut1 = (u16*)d_ws;                              // 3 x 2 MB bf16 planes
    u16*   Ut2 = Ut1 + (size_t)UNITS * UNITS;
    u16*   Ut3 = Ut2 + (size_t)UNITS * UNITS;
    float* xW  = (float*)(Ut3 + (size_t)UNITS * UNITS);   // 104.9 MB
    float* hbuf = xW + (size_t)T_STEPS * BATCH * UNITS;   // 2 x 256 KB fp32
    u32*   flags = (u32*)(hbuf + (size_t)2 * 64 * UNITS); // 256 words

    init_ws<<<64, 256, 0, stream>>>(hbuf, flags);
    u_split_t<<<dim3(32, 32), 256, 0, stream>>>(U, Ut1, Ut2, Ut3);
    xw_gemm<<<dim3(800, 4), 256, 0, stream>>>(inp, W, bias, xW);

    void* args[] = {(void*)&xW, (void*)&Ut1, (void*)&Ut2, (void*)&Ut3,
                    (void*)&hbuf, (void*)&flags, (void*)&out};
    hipLaunchCooperativeKernel((const void*)rnn_scan, dim3(128), dim3(512),
                               args, 0, stream);
}